// Round 9
// baseline (875.856 us; speedup 1.0000x reference)
//
#include <hip/hip_runtime.h>
#include <hip/hip_bf16.h>

// Problem constants
#define CIN  128
#define CO   256
#define HIN  56
#define WIN  56
#define OH   28
#define OWW  28
#define P    784     // 28*28
#define HWIN 3136    // 56*56
#define PERT 200704  // CO*P

typedef __attribute__((ext_vector_type(8))) short bf16x8v;  // 8 bf16 in 4 VGPRs
typedef __attribute__((ext_vector_type(4))) float f32x4;

__device__ __forceinline__ f32x4 mfma16(bf16x8v a, bf16x8v b, f32x4 c) {
    return __builtin_amdgcn_mfma_f32_16x16x32_bf16(a, b, c, 0, 0, 0);
}

// async global->LDS, 16B per lane; LDS dest = wave-uniform base + lane*16
__device__ __forceinline__ void gld_lds16(const void* g, void* l) {
    __builtin_amdgcn_global_load_lds(
        (const __attribute__((address_space(1))) void*)g,
        (__attribute__((address_space(3))) void*)l, 16, 0, 0);
}

// ---------------------------------------------------------------------------
// Prep: BN fold scalars for all three BNs.
// ---------------------------------------------------------------------------
__global__ __launch_bounds__(256) void k_prep_bias(
    const float* __restrict__ g1, const float* __restrict__ b1,
    const float* __restrict__ m1, const float* __restrict__ v1,
    const float* __restrict__ g2, const float* __restrict__ b2,
    const float* __restrict__ m2, const float* __restrict__ v2,
    const float* __restrict__ gd, const float* __restrict__ bd,
    const float* __restrict__ md, const float* __restrict__ vd,
    float* __restrict__ inv1o, float* __restrict__ bias1o,
    float* __restrict__ inv2o, float* __restrict__ invdo,
    float* __restrict__ bias2o)
{
    int co = threadIdx.x;
    float inv1 = g1[co] / sqrtf(v1[co] + 1e-5f);
    float inv2 = g2[co] / sqrtf(v2[co] + 1e-5f);
    float invd = gd[co] / sqrtf(vd[co] + 1e-5f);
    inv1o[co]  = inv1;
    bias1o[co] = fmaf(-m1[co], inv1, b1[co]);
    inv2o[co]  = inv2;
    invdo[co]  = invd;
    bias2o[co] = fmaf(-m2[co], inv2, b2[co]) + fmaf(-md[co], invd, bd[co]);
}

// ---------------------------------------------------------------------------
// Weight repack: fragment-contiguous layout. One wave A-fragment load =
// 64 lanes x 16B contiguous, lane = quad*16 + l15 holds
// w[co = cf*16 + l15][ci = ch*32 + quad*8 + j].
// ---------------------------------------------------------------------------
// w2 -> [tap 9][ch 8][cf 16][lane 64][8] hi/lo (scaled by inv2[co])
__global__ __launch_bounds__(256) void k_prep_w2p(
    const float* __restrict__ w2, const float* __restrict__ inv2,
    unsigned short* __restrict__ hi, unsigned short* __restrict__ lo)
{
    int i = blockIdx.x * 256 + threadIdx.x;       // 9*8*16*64 = 73728
    if (i >= 73728) return;
    int tap = i >> 13;
    int r   = i & 8191;
    int ch  = r >> 10;
    int r2  = r & 1023;
    int cf  = r2 >> 6;
    int lane = r2 & 63;
    int co  = cf * 16 + (lane & 15);
    int cib = ch * 32 + (lane >> 4) * 8;
#pragma unroll
    for (int j = 0; j < 8; j++) {
        float w = w2[((size_t)co * CO + cib + j) * 9 + tap] * inv2[co];
        __hip_bfloat16 h = __float2bfloat16(w);
        __hip_bfloat16 l = __float2bfloat16(w - __bfloat162float(h));
        hi[(size_t)i * 8 + j] = *(unsigned short*)&h;
        lo[(size_t)i * 8 + j] = *(unsigned short*)&l;
    }
}

// w1 -> [tap 9][ch 4][cf 16][lane 64][8] hi/mid/lo (EXACT 3-way split, x inv1)
__global__ __launch_bounds__(256) void k_prep_w1p(
    const float* __restrict__ w1, const float* __restrict__ inv1,
    unsigned short* __restrict__ hi, unsigned short* __restrict__ mid,
    unsigned short* __restrict__ lo)
{
    int i = blockIdx.x * 256 + threadIdx.x;       // 9*4*16*64 = 36864
    if (i >= 36864) return;
    int tap = i >> 12;
    int r   = i & 4095;
    int ch  = r >> 10;
    int r2  = r & 1023;
    int cf  = r2 >> 6;
    int lane = r2 & 63;
    int co  = cf * 16 + (lane & 15);
    int cib = ch * 32 + (lane >> 4) * 8;
#pragma unroll
    for (int j = 0; j < 8; j++) {
        float w = w1[((size_t)co * CIN + cib + j) * 9 + tap] * inv1[co];
        __hip_bfloat16 h = __float2bfloat16(w);
        float r1 = w - __bfloat162float(h);
        __hip_bfloat16 m = __float2bfloat16(r1);
        float r2f = r1 - __bfloat162float(m);
        __hip_bfloat16 l = __float2bfloat16(r2f);
        hi[(size_t)i * 8 + j]  = *(unsigned short*)&h;
        mid[(size_t)i * 8 + j] = *(unsigned short*)&m;
        lo[(size_t)i * 8 + j]  = *(unsigned short*)&l;
    }
}

// wd -> [ch 4][cf 16][lane 64][8] hi/lo (x invd)
__global__ __launch_bounds__(256) void k_prep_wdp(
    const float* __restrict__ wd, const float* __restrict__ invd,
    unsigned short* __restrict__ hi, unsigned short* __restrict__ lo)
{
    int i = blockIdx.x * 256 + threadIdx.x;       // 4*16*64 = 4096
    if (i >= 4096) return;
    int ch  = i >> 10;
    int r2  = i & 1023;
    int cf  = r2 >> 6;
    int lane = r2 & 63;
    int co  = cf * 16 + (lane & 15);
    int cib = ch * 32 + (lane >> 4) * 8;
#pragma unroll
    for (int j = 0; j < 8; j++) {
        float w = wd[(size_t)co * CIN + cib + j] * invd[co];
        __hip_bfloat16 h = __float2bfloat16(w);
        __hip_bfloat16 l = __float2bfloat16(w - __bfloat162float(h));
        hi[(size_t)i * 8 + j] = *(unsigned short*)&h;
        lo[(size_t)i * 8 + j] = *(unsigned short*)&l;
    }
}

// ---------------------------------------------------------------------------
// Pack x (binary fp32 [n][ci][3136]) -> bitmask xt_p [n][3136][4 words].
// ---------------------------------------------------------------------------
__global__ __launch_bounds__(256) void k_pack1(
    const float* __restrict__ x, unsigned int* __restrict__ xt_p)
{
    int i = blockIdx.x * 256 + threadIdx.x;       // ((n*4 + w)*3136 + pos)
    int pos = i % HWIN;
    int nw  = i / HWIN;
    int w   = nw & 3;
    int n   = nw >> 2;
    const float* xp = x + ((size_t)n * CIN + w * 32) * HWIN + pos;
    unsigned int word = 0;
#pragma unroll
    for (int ci = 0; ci < 32; ci++)
        if (xp[(size_t)ci * HWIN] != 0.f) word |= (1u << ci);
    xt_p[((size_t)n * HWIN + pos) * 4 + w] = word;
}

// ---------------------------------------------------------------------------
// conv1 3x3 s2 p1 via bf16 MFMA on bit-packed spikes, EXACT 3x bf16 weights.
// (R8 design — proven)
// ---------------------------------------------------------------------------
__global__ __launch_bounds__(256) void k_conv1_mfma(
    const unsigned int* __restrict__ xt_p,       // [128][3136][4]
    const unsigned short* __restrict__ w1hip,    // [9][4][16][64][8]
    const unsigned short* __restrict__ w1midp,
    const unsigned short* __restrict__ w1lop,
    const float* __restrict__ bias1,
    float* __restrict__ out)                     // [128][256][784] pre-act
{
    __shared__ unsigned int XW[4 * 522];         // [ch][row 9][col 58]

    const int n    = blockIdx.x / 7;
    const int rt   = blockIdx.x - n * 7;
    const int r0   = rt * 4;
    const int tid  = threadIdx.x;
    const int wave = tid >> 6;
    const int lane = tid & 63;
    const int l15  = lane & 15;
    const int quad = lane >> 4;
    const int cf0  = blockIdx.y * 8 + wave * 2;  // co_w = cf0*16

    const unsigned int* xp_n = xt_p + (size_t)n * HWIN * 4;
    for (int i = tid; i < 513; i += 256) {
        int row = i / 57, c = i - row * 57;
        int irow = 2 * r0 - 1 + row;             // [-1, 55]
        int iw   = c - 1;                        // [-1, 55]
        uint4 val = {0u, 0u, 0u, 0u};
        if (irow >= 0 && iw >= 0)
            val = *(const uint4*)(xp_n + (size_t)(irow * WIN + iw) * 4);
        int base = row * 58 + c;
        XW[0 * 522 + base] = val.x;
        XW[1 * 522 + base] = val.y;
        XW[2 * 522 + base] = val.z;
        XW[3 * 522 + base] = val.w;
    }
    __syncthreads();

    int rr[7], cc[7];
#pragma unroll
    for (int f = 0; f < 7; f++) {
        int pos = f * 16 + l15;
        rr[f] = pos / 28;
        cc[f] = pos - rr[f] * 28;
    }

    f32x4 acc[2][7];
#pragma unroll
    for (int g = 0; g < 2; g++)
#pragma unroll
        for (int f = 0; f < 7; f++) acc[g][f] = (f32x4){0.f, 0.f, 0.f, 0.f};

    bf16x8v ch0, cm0, cl0, ch1, cm1, cl1;
    bf16x8v nh0, nm0, nl0, nh1, nm1, nl1;
    {
        size_t b0 = ((size_t)0 * 16 + cf0) * 512 + lane * 8;
        ch0 = *(const bf16x8v*)(w1hip + b0);  cm0 = *(const bf16x8v*)(w1midp + b0);
        cl0 = *(const bf16x8v*)(w1lop + b0);
        ch1 = *(const bf16x8v*)(w1hip + b0 + 512); cm1 = *(const bf16x8v*)(w1midp + b0 + 512);
        cl1 = *(const bf16x8v*)(w1lop + b0 + 512);
        nh0 = ch0; nm0 = cm0; nl0 = cl0; nh1 = ch1; nm1 = cm1; nl1 = cl1;
    }

    for (int c = 0; c < 4; c++) {
        for (int tap = 0; tap < 9; tap++) {
            int rd = c * 9 + tap;
            if (rd < 35) {
                int rn = rd + 1, cn = rn / 9, tn = rn - cn * 9;
                size_t b0 = ((size_t)(tn * 4 + cn) * 16 + cf0) * 512 + lane * 8;
                nh0 = *(const bf16x8v*)(w1hip + b0);  nm0 = *(const bf16x8v*)(w1midp + b0);
                nl0 = *(const bf16x8v*)(w1lop + b0);
                nh1 = *(const bf16x8v*)(w1hip + b0 + 512); nm1 = *(const bf16x8v*)(w1midp + b0 + 512);
                nl1 = *(const bf16x8v*)(w1lop + b0 + 512);
            }
            const int kh = tap / 3, kw = tap - kh * 3;
#pragma unroll
            for (int f = 0; f < 7; f++) {
                unsigned int word = XW[c * 522 + (2 * rr[f] + kh) * 58 + 2 * cc[f] + kw];
                unsigned int byt  = (word >> (quad * 8)) & 0xffu;
                uint4 u;
                u.x = ((byt & 1u)   ? 0x3F80u : 0u) | ((byt & 2u)   ? 0x3F800000u : 0u);
                u.y = ((byt & 4u)   ? 0x3F80u : 0u) | ((byt & 8u)   ? 0x3F800000u : 0u);
                u.z = ((byt & 16u)  ? 0x3F80u : 0u) | ((byt & 32u)  ? 0x3F800000u : 0u);
                u.w = ((byt & 64u)  ? 0x3F80u : 0u) | ((byt & 128u) ? 0x3F800000u : 0u);
                union { uint4 q; bf16x8v v; } cv;
                cv.q = u;
                acc[0][f] = mfma16(ch0, cv.v, acc[0][f]);
                acc[0][f] = mfma16(cm0, cv.v, acc[0][f]);
                acc[0][f] = mfma16(cl0, cv.v, acc[0][f]);
                acc[1][f] = mfma16(ch1, cv.v, acc[1][f]);
                acc[1][f] = mfma16(cm1, cv.v, acc[1][f]);
                acc[1][f] = mfma16(cl1, cv.v, acc[1][f]);
            }
            ch0 = nh0; cm0 = nm0; cl0 = nl0; ch1 = nh1; cm1 = nm1; cl1 = nl1;
        }
    }

#pragma unroll
    for (int g = 0; g < 2; g++)
#pragma unroll
        for (int f = 0; f < 7; f++) {
            int pg = rt * 112 + f * 16 + l15;
#pragma unroll
            for (int reg = 0; reg < 4; reg++) {
                int co = cf0 * 16 + g * 16 + quad * 4 + reg;
                out[((size_t)n * CO + co) * P + pg] = acc[g][f][reg] + bias1[co];
            }
        }
}

// ---------------------------------------------------------------------------
// LIF1 + transpose: pre1 [16][8][256][784] fp32 ->
// spike_t [n][ch 8][pos 784][32ci] bf16, with the 4 ci-octets of each pos
// stored ROTATED by f8(pos) so conv2's DMA-landed LDS reads are conflict-free.
// f8(pos) = ((((oh+1)*30 + ow + 1) >> 1) & 3
// ---------------------------------------------------------------------------
__global__ __launch_bounds__(256) void k_lif1t(
    const float* __restrict__ pre, unsigned short* __restrict__ st)
{
    __shared__ unsigned short T[16 * 68];
    const int b   = blockIdx.x;
    const int co0 = blockIdx.y * 64;
    const int p0  = blockIdx.z * 16;
    const int tid  = threadIdx.x;
    const int pcol = tid & 15;
    const int g    = tid >> 4;
    // octet rotation for output position pos = p0 + g
    const int pos = p0 + g;
    const int oh  = pos / 28, ow = pos - oh * 28;
    const int f8  = ((((oh + 1) * 30 + ow + 1) >> 1) & 3);
    const int o      = (pcol & 7) >> 1;          // source octet
    const int no     = o ^ f8;                   // rotated octet slot
    const int within = (pcol & 1) * 4;
    const int chp    = (co0 >> 5) + (pcol >> 3);
    float v[4] = {0.f, 0.f, 0.f, 0.f};
    for (int t = 0; t < 8; t++) {
        const float* src = pre + (((size_t)(b * 8 + t)) * CO + co0) * P + p0;
        unsigned short s[4];
#pragma unroll
        for (int j = 0; j < 4; j++) {
            int co = g + 16 * j;
            float xv = src[(size_t)co * P + pcol];
            v[j] = v[j] + (xv - v[j]) * 0.5f;
            bool sp = v[j] > 1.0f;
            s[j] = sp ? 0x3F80 : 0;
            if (sp) v[j] = 0.f;
        }
        __syncthreads();
#pragma unroll
        for (int j = 0; j < 4; j++) T[pcol * 68 + g + 16 * j] = s[j];
        __syncthreads();
        unsigned short* dst = st + (((size_t)(b * 8 + t) * 8 + chp) * P + pos) * 32
                               + no * 8 + within;
        ushort4 ov;
        ov.x = T[g * 68 + pcol * 4 + 0];
        ov.y = T[g * 68 + pcol * 4 + 1];
        ov.z = T[g * 68 + pcol * 4 + 2];
        ov.w = T[g * 68 + pcol * 4 + 3];
        *(ushort4*)dst = ov;
    }
}

// ---------------------------------------------------------------------------
// conv2 3x3 s1 p1 + ds 1x1 s2 via bf16 MFMA (BN folded).
// R9: DMA staging (linear, rotated-at-producer) + swizzled conflict-free
// B-reads; ds shortcut from bit-packed x (staged once, register unpack).
// Grid (896, 2); wave = 32 co x 112 pos.
// ---------------------------------------------------------------------------
__global__ __launch_bounds__(256) void k_conv2_mfma(
    const unsigned short* __restrict__ spike_t,  // [128][8][784][32] rotated
    const unsigned int* __restrict__ xt_p,       // [128][3136][4]
    const unsigned short* __restrict__ w2hip,    // [9][8][16][64][8]
    const unsigned short* __restrict__ w2lop,
    const unsigned short* __restrict__ wdhip,    // [4][16][64][8]
    const unsigned short* __restrict__ wdlop,
    const float* __restrict__ bias2,
    float* __restrict__ out)                     // [128][256][784]
{
    __shared__ unsigned short SB[2 * 5760];      // 2 x 11520 B; line = 64B/slot
    __shared__ unsigned int   XW2[4 * 112];      // ds bit-words [ch][112 pos]

    const int n    = blockIdx.x / 7;
    const int rt   = blockIdx.x - n * 7;
    const int r0   = rt * 4;
    const int tid  = threadIdx.x;
    const int wave = tid >> 6;
    const int lane = tid & 63;
    const int l15  = lane & 15;
    const int quad = lane >> 4;
    const int cf0  = blockIdx.y * 8 + wave * 2;  // co_w = cf0*16

    // zero both spike buffers once (halo protocol)
    {
        uint4 z = {0u, 0u, 0u, 0u};
        for (int i = tid; i < 1440; i += 256) ((uint4*)SB)[i] = z;
    }
    // stage ds bit-words once: pos = r*28+c -> x(2*(r0+r), 2c), planes by ch
    for (int i = tid; i < 112; i += 256) {
        int r = i / 28, c = i - r * 28;
        uint4 w4 = *(const uint4*)(xt_p + ((size_t)n * HWIN
                    + (2 * (r0 + r)) * WIN + 2 * c) * 4);
        XW2[0 * 112 + i] = w4.x;
        XW2[1 * 112 + i] = w4.y;
        XW2[2 * 112 + i] = w4.z;
        XW2[3 * 112 + i] = w4.w;
    }
    __syncthreads();

    // DMA geometry (as R8): idx = wave*3+k in [0,12); row = idx>>1, half = idx&1
    int  g_irow[3], g_lds[3];
    bool g_ok[3];
    int  g_half[3];
#pragma unroll
    for (int k = 0; k < 3; k++) {
        int idx  = wave * 3 + k;
        int row  = idx >> 1, half = idx & 1;
        int irow = r0 - 1 + row;
        g_irow[k] = irow;
        g_half[k] = half;
        g_ok[k]   = ((unsigned)irow < 28u) && (half == 0 || lane < 48);
        g_lds[k]  = row * 1920 + 64 + half * 1024;   // wave-uniform
    }
    const char* sp_n = (const char*)spike_t + (size_t)n * 8 * P * 64;

    // stage chunk 0 -> buffer 0
#pragma unroll
    for (int k = 0; k < 3; k++)
        if (g_ok[k])
            gld_lds16(sp_n + (size_t)g_irow[k] * 1792 + g_half[k] * 1024 + lane * 16,
                      (char*)SB + g_lds[k]);
    __syncthreads();

    int rr[7], cc[7];
#pragma unroll
    for (int f = 0; f < 7; f++) {
        int pos = f * 16 + l15;
        rr[f] = pos / 28;
        cc[f] = pos - rr[f] * 28;
    }

    f32x4 acc[2][7];
#pragma unroll
    for (int g = 0; g < 2; g++)
#pragma unroll
        for (int f = 0; f < 7; f++) acc[g][f] = (f32x4){0.f, 0.f, 0.f, 0.f};

    bf16x8v ch0, cl0, ch1, cl1, nh0, nl0, nh1, nl1;
    {
        size_t b0 = ((size_t)0 * 16 + cf0) * 512 + lane * 8;
        ch0 = *(const bf16x8v*)(w2hip + b0);
        cl0 = *(const bf16x8v*)(w2lop + b0);
        ch1 = *(const bf16x8v*)(w2hip + b0 + 512);
        cl1 = *(const bf16x8v*)(w2lop + b0 + 512);
        nh0 = ch0; nl0 = cl0; nh1 = ch1; nl1 = cl1;
    }

    for (int c = 0; c < 8; c++) {
        if (c < 7) {                              // async stage chunk c+1
            const char* base = sp_n + (size_t)(c + 1) * 50176;
            char* dstb = (char*)SB + ((c + 1) & 1) * 11520;
#pragma unroll
            for (int k = 0; k < 3; k++)
                if (g_ok[k])
                    gld_lds16(base + (size_t)g_irow[k] * 1792 + g_half[k] * 1024 + lane * 16,
                              dstb + g_lds[k]);
        }
        const int bufsh = (c & 1) * 5760;
        for (int tap = 0; tap < 9; tap++) {
            int rd = c * 9 + tap;
            if (rd < 71) {
                int rn = rd + 1, cn = rn / 9, tn = rn - cn * 9;
                size_t b0 = ((size_t)(tn * 8 + cn) * 16 + cf0) * 512 + lane * 8;
                nh0 = *(const bf16x8v*)(w2hip + b0);
                nl0 = *(const bf16x8v*)(w2lop + b0);
                nh1 = *(const bf16x8v*)(w2hip + b0 + 512);
                nl1 = *(const bf16x8v*)(w2lop + b0 + 512);
            }
            const int kh = tap / 3, kw = tap - kh * 3;
#pragma unroll
            for (int f = 0; f < 7; f++) {
                int slot = (rr[f] + kh) * 30 + cc[f] + kw;
                int sw   = (slot >> 1) & 3;       // == producer rotation f8
                bf16x8v bfr = *(const bf16x8v*)(
                    &SB[bufsh + slot * 32 + ((quad ^ sw) * 8)]);
                acc[0][f] = mfma16(ch0, bfr, acc[0][f]);
                acc[0][f] = mfma16(cl0, bfr, acc[0][f]);
                acc[1][f] = mfma16(ch1, bfr, acc[1][f]);
                acc[1][f] = mfma16(cl1, bfr, acc[1][f]);
            }
            ch0 = nh0; cl0 = nl0; ch1 = nh1; cl1 = nl1;
        }
        __syncthreads();                          // release buf c, land c+1
    }

    // ds shortcut: bit-unpack from XW2 (no barriers, no LDS writes)
    for (int c = 0; c < 4; c++) {
        size_t b0 = ((size_t)c * 16 + cf0) * 512 + lane * 8;
        bf16x8v a0h = *(const bf16x8v*)(wdhip + b0);
        bf16x8v a0l = *(const bf16x8v*)(wdlop + b0);
        bf16x8v a1h = *(const bf16x8v*)(wdhip + b0 + 512);
        bf16x8v a1l = *(const bf16x8v*)(wdlop + b0 + 512);
#pragma unroll
        for (int f = 0; f < 7; f++) {
            unsigned int word = XW2[c * 112 + rr[f] * 28 + cc[f]];
            unsigned int byt  = (word >> (quad * 8)) & 0xffu;
            uint4 u;
            u.x = ((byt & 1u)   ? 0x3F80u : 0u) | ((byt & 2u)   ? 0x3F800000u : 0u);
            u.y = ((byt & 4u)   ? 0x3F80u : 0u) | ((byt & 8u)   ? 0x3F800000u : 0u);
            u.z = ((byt & 16u)  ? 0x3F80u : 0u) | ((byt & 32u)  ? 0x3F800000u : 0u);
            u.w = ((byt & 64u)  ? 0x3F80u : 0u) | ((byt & 128u) ? 0x3F800000u : 0u);
            union { uint4 q; bf16x8v v; } cv;
            cv.q = u;
            acc[0][f] = mfma16(a0h, cv.v, acc[0][f]);
            acc[0][f] = mfma16(a0l, cv.v, acc[0][f]);
            acc[1][f] = mfma16(a1h, cv.v, acc[1][f]);
            acc[1][f] = mfma16(a1l, cv.v, acc[1][f]);
        }
    }

#pragma unroll
    for (int g = 0; g < 2; g++)
#pragma unroll
        for (int f = 0; f < 7; f++) {
            int pg = rt * 112 + f * 16 + l15;
#pragma unroll
            for (int reg = 0; reg < 4; reg++) {
                int co = cf0 * 16 + g * 16 + quad * 4 + reg;
                out[((size_t)n * CO + co) * P + pg] = acc[g][f][reg] + bias2[co];
            }
        }
}

// ---------------------------------------------------------------------------
// LIF2: in-place over [B=16, T=8, PERT], float4-vectorized
// ---------------------------------------------------------------------------
__global__ __launch_bounds__(256) void k_lif4(const float4* __restrict__ in,
                                              float4* __restrict__ out)
{
    const int q = PERT / 4;                       // 50176
    const int i = blockIdx.x * 256 + threadIdx.x;
    const int b = i / q;
    const int r = i - b * q;
    const float4* pi = in  + (size_t)(b * 8) * q + r;
    float4*       po = out + (size_t)(b * 8) * q + r;
    float v0 = 0.f, v1 = 0.f, v2 = 0.f, v3 = 0.f;
#pragma unroll
    for (int t = 0; t < 8; t++) {
        float4 xt = pi[(size_t)t * q];
        float4 s;
        v0 = v0 + (xt.x - v0) * 0.5f; s.x = (v0 > 1.0f) ? 1.f : 0.f; if (v0 > 1.0f) v0 = 0.f;
        v1 = v1 + (xt.y - v1) * 0.5f; s.y = (v1 > 1.0f) ? 1.f : 0.f; if (v1 > 1.0f) v1 = 0.f;
        v2 = v2 + (xt.z - v2) * 0.5f; s.z = (v2 > 1.0f) ? 1.f : 0.f; if (v2 > 1.0f) v2 = 0.f;
        v3 = v3 + (xt.w - v3) * 0.5f; s.w = (v3 > 1.0f) ? 1.f : 0.f; if (v3 > 1.0f) v3 = 0.f;
        po[(size_t)t * q] = s;
    }
}

extern "C" void kernel_launch(void* const* d_in, const int* in_sizes, int n_in,
                              void* d_out, int out_size, void* d_ws, size_t ws_size,
                              hipStream_t stream) {
    const float* x   = (const float*)d_in[0];
    const float* w1  = (const float*)d_in[1];
    const float* w2  = (const float*)d_in[2];
    const float* wd  = (const float*)d_in[3];
    const float* n1g = (const float*)d_in[4];
    const float* n1b = (const float*)d_in[5];
    const float* n1m = (const float*)d_in[6];
    const float* n1v = (const float*)d_in[7];
    const float* n2g = (const float*)d_in[8];
    const float* n2b = (const float*)d_in[9];
    const float* n2m = (const float*)d_in[10];
    const float* n2v = (const float*)d_in[11];
    const float* ndg = (const float*)d_in[12];
    const float* ndb = (const float*)d_in[13];
    const float* ndm = (const float*)d_in[14];
    const float* ndv = (const float*)d_in[15];

    float* out = (float*)d_out;   // pre1 -> (lif1t) -> pre2 -> final spikes

    // ws layout (1KB-aligned); total ~62.1 MB
    char* w = (char*)d_ws;
    unsigned short* spike_t = (unsigned short*)w;                    // 51,380,224
    unsigned short* w2hip   = (unsigned short*)(w + 51380224);       //  1,179,648
    unsigned short* w2lop   = (unsigned short*)(w + 52559872);       //  1,179,648
    unsigned short* w1hip   = (unsigned short*)(w + 53739520);       //    589,824
    unsigned short* w1midp  = (unsigned short*)(w + 54329344);       //    589,824
    unsigned short* w1lop   = (unsigned short*)(w + 54919168);       //    589,824
    unsigned short* wdhip   = (unsigned short*)(w + 55508992);       //     65,536
    unsigned short* wdlop   = (unsigned short*)(w + 55574528);       //     65,536
    float*          bias2   = (float*)(w + 55640064);
    float*          bias1   = (float*)(w + 55641088);
    float*          inv1    = (float*)(w + 55642112);
    float*          inv2    = (float*)(w + 55643136);
    float*          invd    = (float*)(w + 55644160);
    unsigned int*   xt_p    = (unsigned int*)(w + 55645184);         //  6,422,528

    k_prep_bias<<<1, 256, 0, stream>>>(n1g, n1b, n1m, n1v,
                                       n2g, n2b, n2m, n2v,
                                       ndg, ndb, ndm, ndv,
                                       inv1, bias1, inv2, invd, bias2);
    k_prep_w2p<<<288, 256, 0, stream>>>(w2, inv2, w2hip, w2lop);
    k_prep_w1p<<<144, 256, 0, stream>>>(w1, inv1, w1hip, w1midp, w1lop);
    k_prep_wdp<<<16, 256, 0, stream>>>(wd, invd, wdhip, wdlop);

    k_pack1<<<(128 * 4 * HWIN) / 256, 256, 0, stream>>>(x, xt_p);
    k_conv1_mfma<<<dim3(896, 2), 256, 0, stream>>>(
        xt_p, w1hip, w1midp, w1lop, bias1, out);
    k_lif1t<<<dim3(16, 4, 49), 256, 0, stream>>>(out, spike_t);
    k_conv2_mfma<<<dim3(896, 2), 256, 0, stream>>>(
        spike_t, xt_p, w2hip, w2lop, wdhip, wdlop, bias2, out);
    k_lif4<<<(16 * (PERT / 4)) / 256, 256, 0, stream>>>(
        (const float4*)out, (float4*)out);
}

// Round 10
// 819.956 us; speedup vs baseline: 1.0682x; 1.0682x over previous
//
#include <hip/hip_runtime.h>
#include <hip/hip_bf16.h>

// Problem constants
#define CIN  128
#define CO   256
#define HIN  56
#define WIN  56
#define OH   28
#define OWW  28
#define P    784     // 28*28
#define HWIN 3136    // 56*56
#define PERT 200704  // CO*P

typedef __attribute__((ext_vector_type(8))) short bf16x8v;  // 8 bf16 in 4 VGPRs
typedef __attribute__((ext_vector_type(4))) float f32x4;

__device__ __forceinline__ f32x4 mfma16(bf16x8v a, bf16x8v b, f32x4 c) {
    return __builtin_amdgcn_mfma_f32_16x16x32_bf16(a, b, c, 0, 0, 0);
}

// async global->LDS, 16B per lane; LDS dest = wave-uniform base + lane*16
__device__ __forceinline__ void gld_lds16(const void* g, void* l) {
    __builtin_amdgcn_global_load_lds(
        (const __attribute__((address_space(1))) void*)g,
        (__attribute__((address_space(3))) void*)l, 16, 0, 0);
}

// ---------------------------------------------------------------------------
// Prep: BN fold scalars for all three BNs.
// ---------------------------------------------------------------------------
__global__ __launch_bounds__(256) void k_prep_bias(
    const float* __restrict__ g1, const float* __restrict__ b1,
    const float* __restrict__ m1, const float* __restrict__ v1,
    const float* __restrict__ g2, const float* __restrict__ b2,
    const float* __restrict__ m2, const float* __restrict__ v2,
    const float* __restrict__ gd, const float* __restrict__ bd,
    const float* __restrict__ md, const float* __restrict__ vd,
    float* __restrict__ inv1o, float* __restrict__ bias1o,
    float* __restrict__ inv2o, float* __restrict__ invdo,
    float* __restrict__ bias2o)
{
    int co = threadIdx.x;
    float inv1 = g1[co] / sqrtf(v1[co] + 1e-5f);
    float inv2 = g2[co] / sqrtf(v2[co] + 1e-5f);
    float invd = gd[co] / sqrtf(vd[co] + 1e-5f);
    inv1o[co]  = inv1;
    bias1o[co] = fmaf(-m1[co], inv1, b1[co]);
    inv2o[co]  = inv2;
    invdo[co]  = invd;
    bias2o[co] = fmaf(-m2[co], inv2, b2[co]) + fmaf(-md[co], invd, bd[co]);
}

// ---------------------------------------------------------------------------
// Weight repack: fragment-contiguous layout. One wave A-fragment load =
// 64 lanes x 16B contiguous, lane = quad*16 + l15 holds
// w[co = cf*16 + l15][ci = ch*32 + quad*8 + j].
// ---------------------------------------------------------------------------
// w2 -> [tap 9][ch 8][cf 16][lane 64][8] hi/lo (scaled by inv2[co])
__global__ __launch_bounds__(256) void k_prep_w2p(
    const float* __restrict__ w2, const float* __restrict__ inv2,
    unsigned short* __restrict__ hi, unsigned short* __restrict__ lo)
{
    int i = blockIdx.x * 256 + threadIdx.x;       // 9*8*16*64 = 73728
    if (i >= 73728) return;
    int tap = i >> 13;
    int r   = i & 8191;
    int ch  = r >> 10;
    int r2  = r & 1023;
    int cf  = r2 >> 6;
    int lane = r2 & 63;
    int co  = cf * 16 + (lane & 15);
    int cib = ch * 32 + (lane >> 4) * 8;
#pragma unroll
    for (int j = 0; j < 8; j++) {
        float w = w2[((size_t)co * CO + cib + j) * 9 + tap] * inv2[co];
        __hip_bfloat16 h = __float2bfloat16(w);
        __hip_bfloat16 l = __float2bfloat16(w - __bfloat162float(h));
        hi[(size_t)i * 8 + j] = *(unsigned short*)&h;
        lo[(size_t)i * 8 + j] = *(unsigned short*)&l;
    }
}

// w1 -> [tap 9][ch 4][cf 16][lane 64][8] hi/mid/lo (EXACT 3-way split, x inv1)
__global__ __launch_bounds__(256) void k_prep_w1p(
    const float* __restrict__ w1, const float* __restrict__ inv1,
    unsigned short* __restrict__ hi, unsigned short* __restrict__ mid,
    unsigned short* __restrict__ lo)
{
    int i = blockIdx.x * 256 + threadIdx.x;       // 9*4*16*64 = 36864
    if (i >= 36864) return;
    int tap = i >> 12;
    int r   = i & 4095;
    int ch  = r >> 10;
    int r2  = r & 1023;
    int cf  = r2 >> 6;
    int lane = r2 & 63;
    int co  = cf * 16 + (lane & 15);
    int cib = ch * 32 + (lane >> 4) * 8;
#pragma unroll
    for (int j = 0; j < 8; j++) {
        float w = w1[((size_t)co * CIN + cib + j) * 9 + tap] * inv1[co];
        __hip_bfloat16 h = __float2bfloat16(w);
        float r1 = w - __bfloat162float(h);
        __hip_bfloat16 m = __float2bfloat16(r1);
        float r2f = r1 - __bfloat162float(m);
        __hip_bfloat16 l = __float2bfloat16(r2f);
        hi[(size_t)i * 8 + j]  = *(unsigned short*)&h;
        mid[(size_t)i * 8 + j] = *(unsigned short*)&m;
        lo[(size_t)i * 8 + j]  = *(unsigned short*)&l;
    }
}

// wd -> [ch 4][cf 16][lane 64][8] hi/lo (x invd)
__global__ __launch_bounds__(256) void k_prep_wdp(
    const float* __restrict__ wd, const float* __restrict__ invd,
    unsigned short* __restrict__ hi, unsigned short* __restrict__ lo)
{
    int i = blockIdx.x * 256 + threadIdx.x;       // 4*16*64 = 4096
    if (i >= 4096) return;
    int ch  = i >> 10;
    int r2  = i & 1023;
    int cf  = r2 >> 6;
    int lane = r2 & 63;
    int co  = cf * 16 + (lane & 15);
    int cib = ch * 32 + (lane >> 4) * 8;
#pragma unroll
    for (int j = 0; j < 8; j++) {
        float w = wd[(size_t)co * CIN + cib + j] * invd[co];
        __hip_bfloat16 h = __float2bfloat16(w);
        __hip_bfloat16 l = __float2bfloat16(w - __bfloat162float(h));
        hi[(size_t)i * 8 + j] = *(unsigned short*)&h;
        lo[(size_t)i * 8 + j] = *(unsigned short*)&l;
    }
}

// ---------------------------------------------------------------------------
// Pack x (binary fp32 [n][ci][3136]) -> bitmask xt_p [n][3136][4 words].
// ---------------------------------------------------------------------------
__global__ __launch_bounds__(256) void k_pack1(
    const float* __restrict__ x, unsigned int* __restrict__ xt_p)
{
    int i = blockIdx.x * 256 + threadIdx.x;       // ((n*4 + w)*3136 + pos)
    int pos = i % HWIN;
    int nw  = i / HWIN;
    int w   = nw & 3;
    int n   = nw >> 2;
    const float* xp = x + ((size_t)n * CIN + w * 32) * HWIN + pos;
    unsigned int word = 0;
#pragma unroll
    for (int ci = 0; ci < 32; ci++)
        if (xp[(size_t)ci * HWIN] != 0.f) word |= (1u << ci);
    xt_p[((size_t)n * HWIN + pos) * 4 + w] = word;
}

// ---------------------------------------------------------------------------
// conv1 3x3 s2 p1 via bf16 MFMA on bit-packed spikes, EXACT 3x bf16 weights.
// (R8 design — proven)
// ---------------------------------------------------------------------------
__global__ __launch_bounds__(256) void k_conv1_mfma(
    const unsigned int* __restrict__ xt_p,       // [128][3136][4]
    const unsigned short* __restrict__ w1hip,    // [9][4][16][64][8]
    const unsigned short* __restrict__ w1midp,
    const unsigned short* __restrict__ w1lop,
    const float* __restrict__ bias1,
    float* __restrict__ out)                     // [128][256][784] pre-act
{
    __shared__ unsigned int XW[4 * 522];         // [ch][row 9][col 58]

    const int n    = blockIdx.x / 7;
    const int rt   = blockIdx.x - n * 7;
    const int r0   = rt * 4;
    const int tid  = threadIdx.x;
    const int wave = tid >> 6;
    const int lane = tid & 63;
    const int l15  = lane & 15;
    const int quad = lane >> 4;
    const int cf0  = blockIdx.y * 8 + wave * 2;  // co_w = cf0*16

    const unsigned int* xp_n = xt_p + (size_t)n * HWIN * 4;
    for (int i = tid; i < 513; i += 256) {
        int row = i / 57, c = i - row * 57;
        int irow = 2 * r0 - 1 + row;             // [-1, 55]
        int iw   = c - 1;                        // [-1, 55]
        uint4 val = {0u, 0u, 0u, 0u};
        if (irow >= 0 && iw >= 0)
            val = *(const uint4*)(xp_n + (size_t)(irow * WIN + iw) * 4);
        int base = row * 58 + c;
        XW[0 * 522 + base] = val.x;
        XW[1 * 522 + base] = val.y;
        XW[2 * 522 + base] = val.z;
        XW[3 * 522 + base] = val.w;
    }
    __syncthreads();

    int rr[7], cc[7];
#pragma unroll
    for (int f = 0; f < 7; f++) {
        int pos = f * 16 + l15;
        rr[f] = pos / 28;
        cc[f] = pos - rr[f] * 28;
    }

    f32x4 acc[2][7];
#pragma unroll
    for (int g = 0; g < 2; g++)
#pragma unroll
        for (int f = 0; f < 7; f++) acc[g][f] = (f32x4){0.f, 0.f, 0.f, 0.f};

    bf16x8v ch0, cm0, cl0, ch1, cm1, cl1;
    bf16x8v nh0, nm0, nl0, nh1, nm1, nl1;
    {
        size_t b0 = ((size_t)0 * 16 + cf0) * 512 + lane * 8;
        ch0 = *(const bf16x8v*)(w1hip + b0);  cm0 = *(const bf16x8v*)(w1midp + b0);
        cl0 = *(const bf16x8v*)(w1lop + b0);
        ch1 = *(const bf16x8v*)(w1hip + b0 + 512); cm1 = *(const bf16x8v*)(w1midp + b0 + 512);
        cl1 = *(const bf16x8v*)(w1lop + b0 + 512);
        nh0 = ch0; nm0 = cm0; nl0 = cl0; nh1 = ch1; nm1 = cm1; nl1 = cl1;
    }

    for (int c = 0; c < 4; c++) {
        for (int tap = 0; tap < 9; tap++) {
            int rd = c * 9 + tap;
            if (rd < 35) {
                int rn = rd + 1, cn = rn / 9, tn = rn - cn * 9;
                size_t b0 = ((size_t)(tn * 4 + cn) * 16 + cf0) * 512 + lane * 8;
                nh0 = *(const bf16x8v*)(w1hip + b0);  nm0 = *(const bf16x8v*)(w1midp + b0);
                nl0 = *(const bf16x8v*)(w1lop + b0);
                nh1 = *(const bf16x8v*)(w1hip + b0 + 512); nm1 = *(const bf16x8v*)(w1midp + b0 + 512);
                nl1 = *(const bf16x8v*)(w1lop + b0 + 512);
            }
            const int kh = tap / 3, kw = tap - kh * 3;
#pragma unroll
            for (int f = 0; f < 7; f++) {
                unsigned int word = XW[c * 522 + (2 * rr[f] + kh) * 58 + 2 * cc[f] + kw];
                unsigned int byt  = (word >> (quad * 8)) & 0xffu;
                uint4 u;
                u.x = ((byt & 1u)   ? 0x3F80u : 0u) | ((byt & 2u)   ? 0x3F800000u : 0u);
                u.y = ((byt & 4u)   ? 0x3F80u : 0u) | ((byt & 8u)   ? 0x3F800000u : 0u);
                u.z = ((byt & 16u)  ? 0x3F80u : 0u) | ((byt & 32u)  ? 0x3F800000u : 0u);
                u.w = ((byt & 64u)  ? 0x3F80u : 0u) | ((byt & 128u) ? 0x3F800000u : 0u);
                union { uint4 q; bf16x8v v; } cv;
                cv.q = u;
                acc[0][f] = mfma16(ch0, cv.v, acc[0][f]);
                acc[0][f] = mfma16(cm0, cv.v, acc[0][f]);
                acc[0][f] = mfma16(cl0, cv.v, acc[0][f]);
                acc[1][f] = mfma16(ch1, cv.v, acc[1][f]);
                acc[1][f] = mfma16(cm1, cv.v, acc[1][f]);
                acc[1][f] = mfma16(cl1, cv.v, acc[1][f]);
            }
            ch0 = nh0; cm0 = nm0; cl0 = nl0; ch1 = nh1; cm1 = nm1; cl1 = nl1;
        }
    }

#pragma unroll
    for (int g = 0; g < 2; g++)
#pragma unroll
        for (int f = 0; f < 7; f++) {
            int pg = rt * 112 + f * 16 + l15;
#pragma unroll
            for (int reg = 0; reg < 4; reg++) {
                int co = cf0 * 16 + g * 16 + quad * 4 + reg;
                out[((size_t)n * CO + co) * P + pg] = acc[g][f][reg] + bias1[co];
            }
        }
}

// ---------------------------------------------------------------------------
// LIF1 + transpose: pre1 [16][8][256][784] fp32 ->
// spike_t [n][ch 8][pos 784][32ci] bf16, with the 4 ci-octets of each pos
// stored ROTATED by f8(pos) = ((((oh+1)*30 + ow + 1) >> 1) & 3 so conv2's
// DMA-landed LDS reads are conflict-free.
// ---------------------------------------------------------------------------
__global__ __launch_bounds__(256) void k_lif1t(
    const float* __restrict__ pre, unsigned short* __restrict__ st)
{
    __shared__ unsigned short T[16 * 68];
    const int b   = blockIdx.x;
    const int co0 = blockIdx.y * 64;
    const int p0  = blockIdx.z * 16;
    const int tid  = threadIdx.x;
    const int pcol = tid & 15;
    const int g    = tid >> 4;
    const int pos = p0 + g;
    const int oh  = pos / 28, ow = pos - oh * 28;
    const int f8  = ((((oh + 1) * 30 + ow + 1) >> 1) & 3);
    const int o      = (pcol & 7) >> 1;          // source octet
    const int no     = o ^ f8;                   // rotated octet slot
    const int within = (pcol & 1) * 4;
    const int chp    = (co0 >> 5) + (pcol >> 3);
    float v[4] = {0.f, 0.f, 0.f, 0.f};
    for (int t = 0; t < 8; t++) {
        const float* src = pre + (((size_t)(b * 8 + t)) * CO + co0) * P + p0;
        unsigned short s[4];
#pragma unroll
        for (int j = 0; j < 4; j++) {
            int co = g + 16 * j;
            float xv = src[(size_t)co * P + pcol];
            v[j] = v[j] + (xv - v[j]) * 0.5f;
            bool sp = v[j] > 1.0f;
            s[j] = sp ? 0x3F80 : 0;
            if (sp) v[j] = 0.f;
        }
        __syncthreads();
#pragma unroll
        for (int j = 0; j < 4; j++) T[pcol * 68 + g + 16 * j] = s[j];
        __syncthreads();
        unsigned short* dst = st + (((size_t)(b * 8 + t) * 8 + chp) * P + pos) * 32
                               + no * 8 + within;
        ushort4 ov;
        ov.x = T[g * 68 + pcol * 4 + 0];
        ov.y = T[g * 68 + pcol * 4 + 1];
        ov.z = T[g * 68 + pcol * 4 + 2];
        ov.w = T[g * 68 + pcol * 4 + 3];
        *(ushort4*)dst = ov;
    }
}

// ---------------------------------------------------------------------------
// conv2 3x3 s1 p1 + ds 1x1 s2 via bf16 MFMA (BN folded).
// R10: ds phase FIRST (acc init) so its weight regs die before the K-loop;
// chunk-0 DMA issued before ds so HBM latency hides under ds compute.
// DMA staging linear (rotation at producer) + swizzled conflict-free reads.
// Grid (896, 2); wave = 32 co x 112 pos.
// ---------------------------------------------------------------------------
__global__ __launch_bounds__(256) void k_conv2_mfma(
    const unsigned short* __restrict__ spike_t,  // [128][8][784][32] rotated
    const unsigned int* __restrict__ xt_p,       // [128][3136][4]
    const unsigned short* __restrict__ w2hip,    // [9][8][16][64][8]
    const unsigned short* __restrict__ w2lop,
    const unsigned short* __restrict__ wdhip,    // [4][16][64][8]
    const unsigned short* __restrict__ wdlop,
    const float* __restrict__ bias2,
    float* __restrict__ out)                     // [128][256][784]
{
    __shared__ unsigned short SB[2 * 5760];      // 2 x 11520 B; line = 64B/slot
    __shared__ unsigned int   XW2[4 * 112];      // ds bit-words [ch][112 pos]

    const int n    = blockIdx.x / 7;
    const int rt   = blockIdx.x - n * 7;
    const int r0   = rt * 4;
    const int tid  = threadIdx.x;
    const int wave = tid >> 6;
    const int lane = tid & 63;
    const int l15  = lane & 15;
    const int quad = lane >> 4;
    const int cf0  = blockIdx.y * 8 + wave * 2;  // co_w = cf0*16

    // zero both spike buffers (halo protocol) + stage ds bit-words
    {
        uint4 z = {0u, 0u, 0u, 0u};
        for (int i = tid; i < 1440; i += 256) ((uint4*)SB)[i] = z;
    }
    for (int i = tid; i < 112; i += 256) {
        int r = i / 28, c = i - r * 28;
        uint4 w4 = *(const uint4*)(xt_p + ((size_t)n * HWIN
                    + (2 * (r0 + r)) * WIN + 2 * c) * 4);
        XW2[0 * 112 + i] = w4.x;
        XW2[1 * 112 + i] = w4.y;
        XW2[2 * 112 + i] = w4.z;
        XW2[3 * 112 + i] = w4.w;
    }
    __syncthreads();                              // zeros + XW2 visible

    // DMA geometry: idx = wave*3+k in [0,12); row = idx>>1, half = idx&1
    int  g_irow[3], g_lds[3];
    bool g_ok[3];
    int  g_half[3];
#pragma unroll
    for (int k = 0; k < 3; k++) {
        int idx  = wave * 3 + k;
        int row  = idx >> 1, half = idx & 1;
        int irow = r0 - 1 + row;
        g_irow[k] = irow;
        g_half[k] = half;
        g_ok[k]   = ((unsigned)irow < 28u) && (half == 0 || lane < 48);
        g_lds[k]  = row * 1920 + 64 + half * 1024;   // wave-uniform
    }
    const char* sp_n = (const char*)spike_t + (size_t)n * 8 * P * 64;

    // issue chunk-0 DMA now; latency hides under the ds phase below
#pragma unroll
    for (int k = 0; k < 3; k++)
        if (g_ok[k])
            gld_lds16(sp_n + (size_t)g_irow[k] * 1792 + g_half[k] * 1024 + lane * 16,
                      (char*)SB + g_lds[k]);

    int rr[7], cc[7];
#pragma unroll
    for (int f = 0; f < 7; f++) {
        int pos = f * 16 + l15;
        rr[f] = pos / 28;
        cc[f] = pos - rr[f] * 28;
    }

    f32x4 acc[2][7];
#pragma unroll
    for (int g = 0; g < 2; g++)
#pragma unroll
        for (int f = 0; f < 7; f++) acc[g][f] = (f32x4){0.f, 0.f, 0.f, 0.f};

    // ---- ds phase (acc init): bit-unpack from XW2, wd regs die after ----
    for (int c = 0; c < 4; c++) {
        size_t b0 = ((size_t)c * 16 + cf0) * 512 + lane * 8;
        bf16x8v a0h = *(const bf16x8v*)(wdhip + b0);
        bf16x8v a0l = *(const bf16x8v*)(wdlop + b0);
        bf16x8v a1h = *(const bf16x8v*)(wdhip + b0 + 512);
        bf16x8v a1l = *(const bf16x8v*)(wdlop + b0 + 512);
#pragma unroll
        for (int f = 0; f < 7; f++) {
            unsigned int word = XW2[c * 112 + rr[f] * 28 + cc[f]];
            unsigned int byt  = (word >> (quad * 8)) & 0xffu;
            uint4 u;
            u.x = ((byt & 1u)   ? 0x3F80u : 0u) | ((byt & 2u)   ? 0x3F800000u : 0u);
            u.y = ((byt & 4u)   ? 0x3F80u : 0u) | ((byt & 8u)   ? 0x3F800000u : 0u);
            u.z = ((byt & 16u)  ? 0x3F80u : 0u) | ((byt & 32u)  ? 0x3F800000u : 0u);
            u.w = ((byt & 64u)  ? 0x3F80u : 0u) | ((byt & 128u) ? 0x3F800000u : 0u);
            union { uint4 q; bf16x8v v; } cv;
            cv.q = u;
            acc[0][f] = mfma16(a0h, cv.v, acc[0][f]);
            acc[0][f] = mfma16(a0l, cv.v, acc[0][f]);
            acc[1][f] = mfma16(a1h, cv.v, acc[1][f]);
            acc[1][f] = mfma16(a1l, cv.v, acc[1][f]);
        }
    }
    __syncthreads();                              // drains chunk-0 DMA too

    // ---- main conv loop, double-buffered DMA, weight reg prefetch ----
    bf16x8v ch0, cl0, ch1, cl1, nh0, nl0, nh1, nl1;
    {
        size_t b0 = ((size_t)0 * 16 + cf0) * 512 + lane * 8;
        ch0 = *(const bf16x8v*)(w2hip + b0);
        cl0 = *(const bf16x8v*)(w2lop + b0);
        ch1 = *(const bf16x8v*)(w2hip + b0 + 512);
        cl1 = *(const bf16x8v*)(w2lop + b0 + 512);
        nh0 = ch0; nl0 = cl0; nh1 = ch1; nl1 = cl1;
    }

    for (int c = 0; c < 8; c++) {
        if (c < 7) {                              // async stage chunk c+1
            const char* base = sp_n + (size_t)(c + 1) * 50176;
            char* dstb = (char*)SB + ((c + 1) & 1) * 11520;
#pragma unroll
            for (int k = 0; k < 3; k++)
                if (g_ok[k])
                    gld_lds16(base + (size_t)g_irow[k] * 1792 + g_half[k] * 1024 + lane * 16,
                              dstb + g_lds[k]);
        }
        const int bufsh = (c & 1) * 5760;
        for (int tap = 0; tap < 9; tap++) {
            int rd = c * 9 + tap;
            if (rd < 71) {
                int rn = rd + 1, cn = rn / 9, tn = rn - cn * 9;
                size_t b0 = ((size_t)(tn * 8 + cn) * 16 + cf0) * 512 + lane * 8;
                nh0 = *(const bf16x8v*)(w2hip + b0);
                nl0 = *(const bf16x8v*)(w2lop + b0);
                nh1 = *(const bf16x8v*)(w2hip + b0 + 512);
                nl1 = *(const bf16x8v*)(w2lop + b0 + 512);
            }
            const int kh = tap / 3, kw = tap - kh * 3;
#pragma unroll
            for (int f = 0; f < 7; f++) {
                int slot = (rr[f] + kh) * 30 + cc[f] + kw;
                int sw   = (slot >> 1) & 3;       // == producer rotation f8
                bf16x8v bfr = *(const bf16x8v*)(
                    &SB[bufsh + slot * 32 + ((quad ^ sw) * 8)]);
                acc[0][f] = mfma16(ch0, bfr, acc[0][f]);
                acc[0][f] = mfma16(cl0, bfr, acc[0][f]);
                acc[1][f] = mfma16(ch1, bfr, acc[1][f]);
                acc[1][f] = mfma16(cl1, bfr, acc[1][f]);
            }
            ch0 = nh0; cl0 = nl0; ch1 = nh1; cl1 = nl1;
        }
        __syncthreads();                          // release buf c, land c+1
    }

#pragma unroll
    for (int g = 0; g < 2; g++)
#pragma unroll
        for (int f = 0; f < 7; f++) {
            int pg = rt * 112 + f * 16 + l15;
#pragma unroll
            for (int reg = 0; reg < 4; reg++) {
                int co = cf0 * 16 + g * 16 + quad * 4 + reg;
                out[((size_t)n * CO + co) * P + pg] = acc[g][f][reg] + bias2[co];
            }
        }
}

// ---------------------------------------------------------------------------
// LIF2: in-place over [B=16, T=8, PERT], float4-vectorized
// ---------------------------------------------------------------------------
__global__ __launch_bounds__(256) void k_lif4(const float4* __restrict__ in,
                                              float4* __restrict__ out)
{
    const int q = PERT / 4;                       // 50176
    const int i = blockIdx.x * 256 + threadIdx.x;
    const int b = i / q;
    const int r = i - b * q;
    const float4* pi = in  + (size_t)(b * 8) * q + r;
    float4*       po = out + (size_t)(b * 8) * q + r;
    float v0 = 0.f, v1 = 0.f, v2 = 0.f, v3 = 0.f;
#pragma unroll
    for (int t = 0; t < 8; t++) {
        float4 xt = pi[(size_t)t * q];
        float4 s;
        v0 = v0 + (xt.x - v0) * 0.5f; s.x = (v0 > 1.0f) ? 1.f : 0.f; if (v0 > 1.0f) v0 = 0.f;
        v1 = v1 + (xt.y - v1) * 0.5f; s.y = (v1 > 1.0f) ? 1.f : 0.f; if (v1 > 1.0f) v1 = 0.f;
        v2 = v2 + (xt.z - v2) * 0.5f; s.z = (v2 > 1.0f) ? 1.f : 0.f; if (v2 > 1.0f) v2 = 0.f;
        v3 = v3 + (xt.w - v3) * 0.5f; s.w = (v3 > 1.0f) ? 1.f : 0.f; if (v3 > 1.0f) v3 = 0.f;
        po[(size_t)t * q] = s;
    }
}

extern "C" void kernel_launch(void* const* d_in, const int* in_sizes, int n_in,
                              void* d_out, int out_size, void* d_ws, size_t ws_size,
                              hipStream_t stream) {
    const float* x   = (const float*)d_in[0];
    const float* w1  = (const float*)d_in[1];
    const float* w2  = (const float*)d_in[2];
    const float* wd  = (const float*)d_in[3];
    const float* n1g = (const float*)d_in[4];
    const float* n1b = (const float*)d_in[5];
    const float* n1m = (const float*)d_in[6];
    const float* n1v = (const float*)d_in[7];
    const float* n2g = (const float*)d_in[8];
    const float* n2b = (const float*)d_in[9];
    const float* n2m = (const float*)d_in[10];
    const float* n2v = (const float*)d_in[11];
    const float* ndg = (const float*)d_in[12];
    const float* ndb = (const float*)d_in[13];
    const float* ndm = (const float*)d_in[14];
    const float* ndv = (const float*)d_in[15];

    float* out = (float*)d_out;   // pre1 -> (lif1t) -> pre2 -> final spikes

    // ws layout (1KB-aligned); total ~62.1 MB
    char* w = (char*)d_ws;
    unsigned short* spike_t = (unsigned short*)w;                    // 51,380,224
    unsigned short* w2hip   = (unsigned short*)(w + 51380224);       //  1,179,648
    unsigned short* w2lop   = (unsigned short*)(w + 52559872);       //  1,179,648
    unsigned short* w1hip   = (unsigned short*)(w + 53739520);       //    589,824
    unsigned short* w1midp  = (unsigned short*)(w + 54329344);       //    589,824
    unsigned short* w1lop   = (unsigned short*)(w + 54919168);       //    589,824
    unsigned short* wdhip   = (unsigned short*)(w + 55508992);       //     65,536
    unsigned short* wdlop   = (unsigned short*)(w + 55574528);       //     65,536
    float*          bias2   = (float*)(w + 55640064);
    float*          bias1   = (float*)(w + 55641088);
    float*          inv1    = (float*)(w + 55642112);
    float*          inv2    = (float*)(w + 55643136);
    float*          invd    = (float*)(w + 55644160);
    unsigned int*   xt_p    = (unsigned int*)(w + 55645184);         //  6,422,528

    k_prep_bias<<<1, 256, 0, stream>>>(n1g, n1b, n1m, n1v,
                                       n2g, n2b, n2m, n2v,
                                       ndg, ndb, ndm, ndv,
                                       inv1, bias1, inv2, invd, bias2);
    k_prep_w2p<<<288, 256, 0, stream>>>(w2, inv2, w2hip, w2lop);
    k_prep_w1p<<<144, 256, 0, stream>>>(w1, inv1, w1hip, w1midp, w1lop);
    k_prep_wdp<<<16, 256, 0, stream>>>(wd, invd, wdhip, wdlop);

    k_pack1<<<(128 * 4 * HWIN) / 256, 256, 0, stream>>>(x, xt_p);
    k_conv1_mfma<<<dim3(896, 2), 256, 0, stream>>>(
        xt_p, w1hip, w1midp, w1lop, bias1, out);
    k_lif1t<<<dim3(16, 4, 49), 256, 0, stream>>>(out, spike_t);
    k_conv2_mfma<<<dim3(896, 2), 256, 0, stream>>>(
        spike_t, xt_p, w2hip, w2lop, wdhip, wdlop, bias2, out);
    k_lif4<<<(16 * (PERT / 4)) / 256, 256, 0, stream>>>(
        (const float4*)out, (float4*)out);
}

// Round 11
// 709.990 us; speedup vs baseline: 1.2336x; 1.1549x over previous
//
#include <hip/hip_runtime.h>
#include <hip/hip_bf16.h>

// Problem constants
#define CIN  128
#define CO   256
#define HIN  56
#define WIN  56
#define OH   28
#define OWW  28
#define P    784     // 28*28
#define HWIN 3136    // 56*56
#define PERT 200704  // CO*P

typedef __attribute__((ext_vector_type(8))) short bf16x8v;  // 8 bf16 in 4 VGPRs
typedef __attribute__((ext_vector_type(4))) float f32x4;

__device__ __forceinline__ f32x4 mfma16(bf16x8v a, bf16x8v b, f32x4 c) {
    return __builtin_amdgcn_mfma_f32_16x16x32_bf16(a, b, c, 0, 0, 0);
}

// async global->LDS, 16B per lane; LDS dest = wave-uniform base + lane*16
__device__ __forceinline__ void gld_lds16(const void* g, void* l) {
    __builtin_amdgcn_global_load_lds(
        (const __attribute__((address_space(1))) void*)g,
        (__attribute__((address_space(3))) void*)l, 16, 0, 0);
}

// ---------------------------------------------------------------------------
// Prep: BN fold scalars for all three BNs.
// ---------------------------------------------------------------------------
__global__ __launch_bounds__(256) void k_prep_bias(
    const float* __restrict__ g1, const float* __restrict__ b1,
    const float* __restrict__ m1, const float* __restrict__ v1,
    const float* __restrict__ g2, const float* __restrict__ b2,
    const float* __restrict__ m2, const float* __restrict__ v2,
    const float* __restrict__ gd, const float* __restrict__ bd,
    const float* __restrict__ md, const float* __restrict__ vd,
    float* __restrict__ inv1o, float* __restrict__ bias1o,
    float* __restrict__ inv2o, float* __restrict__ invdo,
    float* __restrict__ bias2o)
{
    int co = threadIdx.x;
    float inv1 = g1[co] / sqrtf(v1[co] + 1e-5f);
    float inv2 = g2[co] / sqrtf(v2[co] + 1e-5f);
    float invd = gd[co] / sqrtf(vd[co] + 1e-5f);
    inv1o[co]  = inv1;
    bias1o[co] = fmaf(-m1[co], inv1, b1[co]);
    inv2o[co]  = inv2;
    invdo[co]  = invd;
    bias2o[co] = fmaf(-m2[co], inv2, b2[co]) + fmaf(-md[co], invd, bd[co]);
}

// ---------------------------------------------------------------------------
// Weight repack: fragment-contiguous layout. One wave A-fragment load =
// 64 lanes x 16B contiguous, lane = quad*16 + l15 holds
// w[co = cf*16 + l15][ci = ch*32 + quad*8 + j].
// ---------------------------------------------------------------------------
// w2 -> [tap 9][ch 8][cf 16][lane 64][8] hi/lo (scaled by inv2[co])
__global__ __launch_bounds__(256) void k_prep_w2p(
    const float* __restrict__ w2, const float* __restrict__ inv2,
    unsigned short* __restrict__ hi, unsigned short* __restrict__ lo)
{
    int i = blockIdx.x * 256 + threadIdx.x;       // 9*8*16*64 = 73728
    if (i >= 73728) return;
    int tap = i >> 13;
    int r   = i & 8191;
    int ch  = r >> 10;
    int r2  = r & 1023;
    int cf  = r2 >> 6;
    int lane = r2 & 63;
    int co  = cf * 16 + (lane & 15);
    int cib = ch * 32 + (lane >> 4) * 8;
#pragma unroll
    for (int j = 0; j < 8; j++) {
        float w = w2[((size_t)co * CO + cib + j) * 9 + tap] * inv2[co];
        __hip_bfloat16 h = __float2bfloat16(w);
        __hip_bfloat16 l = __float2bfloat16(w - __bfloat162float(h));
        hi[(size_t)i * 8 + j] = *(unsigned short*)&h;
        lo[(size_t)i * 8 + j] = *(unsigned short*)&l;
    }
}

// w1 -> [tap 9][ch 4][cf 16][lane 64][8] hi/mid/lo (EXACT 3-way split, x inv1)
__global__ __launch_bounds__(256) void k_prep_w1p(
    const float* __restrict__ w1, const float* __restrict__ inv1,
    unsigned short* __restrict__ hi, unsigned short* __restrict__ mid,
    unsigned short* __restrict__ lo)
{
    int i = blockIdx.x * 256 + threadIdx.x;       // 9*4*16*64 = 36864
    if (i >= 36864) return;
    int tap = i >> 12;
    int r   = i & 4095;
    int ch  = r >> 10;
    int r2  = r & 1023;
    int cf  = r2 >> 6;
    int lane = r2 & 63;
    int co  = cf * 16 + (lane & 15);
    int cib = ch * 32 + (lane >> 4) * 8;
#pragma unroll
    for (int j = 0; j < 8; j++) {
        float w = w1[((size_t)co * CIN + cib + j) * 9 + tap] * inv1[co];
        __hip_bfloat16 h = __float2bfloat16(w);
        float r1 = w - __bfloat162float(h);
        __hip_bfloat16 m = __float2bfloat16(r1);
        float r2f = r1 - __bfloat162float(m);
        __hip_bfloat16 l = __float2bfloat16(r2f);
        hi[(size_t)i * 8 + j]  = *(unsigned short*)&h;
        mid[(size_t)i * 8 + j] = *(unsigned short*)&m;
        lo[(size_t)i * 8 + j]  = *(unsigned short*)&l;
    }
}

// wd -> [ch 4][cf 16][lane 64][8] hi/lo (x invd)
__global__ __launch_bounds__(256) void k_prep_wdp(
    const float* __restrict__ wd, const float* __restrict__ invd,
    unsigned short* __restrict__ hi, unsigned short* __restrict__ lo)
{
    int i = blockIdx.x * 256 + threadIdx.x;       // 4*16*64 = 4096
    if (i >= 4096) return;
    int ch  = i >> 10;
    int r2  = i & 1023;
    int cf  = r2 >> 6;
    int lane = r2 & 63;
    int co  = cf * 16 + (lane & 15);
    int cib = ch * 32 + (lane >> 4) * 8;
#pragma unroll
    for (int j = 0; j < 8; j++) {
        float w = wd[(size_t)co * CIN + cib + j] * invd[co];
        __hip_bfloat16 h = __float2bfloat16(w);
        __hip_bfloat16 l = __float2bfloat16(w - __bfloat162float(h));
        hi[(size_t)i * 8 + j] = *(unsigned short*)&h;
        lo[(size_t)i * 8 + j] = *(unsigned short*)&l;
    }
}

// ---------------------------------------------------------------------------
// Pack x (binary fp32 [n][ci][3136]) -> bitmask xt_p [n][3136][4 words].
// ---------------------------------------------------------------------------
__global__ __launch_bounds__(256) void k_pack1(
    const float* __restrict__ x, unsigned int* __restrict__ xt_p)
{
    int i = blockIdx.x * 256 + threadIdx.x;       // ((n*4 + w)*3136 + pos)
    int pos = i % HWIN;
    int nw  = i / HWIN;
    int w   = nw & 3;
    int n   = nw >> 2;
    const float* xp = x + ((size_t)n * CIN + w * 32) * HWIN + pos;
    unsigned int word = 0;
#pragma unroll
    for (int ci = 0; ci < 32; ci++)
        if (xp[(size_t)ci * HWIN] != 0.f) word |= (1u << ci);
    xt_p[((size_t)n * HWIN + pos) * 4 + w] = word;
}

// ---------------------------------------------------------------------------
// conv1 3x3 s2 p1 via bf16 MFMA on bit-packed spikes, EXACT 3x bf16 weights.
// (R8 design — proven, unchanged)
// ---------------------------------------------------------------------------
__global__ __launch_bounds__(256) void k_conv1_mfma(
    const unsigned int* __restrict__ xt_p,       // [128][3136][4]
    const unsigned short* __restrict__ w1hip,    // [9][4][16][64][8]
    const unsigned short* __restrict__ w1midp,
    const unsigned short* __restrict__ w1lop,
    const float* __restrict__ bias1,
    float* __restrict__ out)                     // [128][256][784] pre-act
{
    __shared__ unsigned int XW[4 * 522];         // [ch][row 9][col 58]

    const int n    = blockIdx.x / 7;
    const int rt   = blockIdx.x - n * 7;
    const int r0   = rt * 4;
    const int tid  = threadIdx.x;
    const int wave = tid >> 6;
    const int lane = tid & 63;
    const int l15  = lane & 15;
    const int quad = lane >> 4;
    const int cf0  = blockIdx.y * 8 + wave * 2;  // co_w = cf0*16

    const unsigned int* xp_n = xt_p + (size_t)n * HWIN * 4;
    for (int i = tid; i < 513; i += 256) {
        int row = i / 57, c = i - row * 57;
        int irow = 2 * r0 - 1 + row;             // [-1, 55]
        int iw   = c - 1;                        // [-1, 55]
        uint4 val = {0u, 0u, 0u, 0u};
        if (irow >= 0 && iw >= 0)
            val = *(const uint4*)(xp_n + (size_t)(irow * WIN + iw) * 4);
        int base = row * 58 + c;
        XW[0 * 522 + base] = val.x;
        XW[1 * 522 + base] = val.y;
        XW[2 * 522 + base] = val.z;
        XW[3 * 522 + base] = val.w;
    }
    __syncthreads();

    int rr[7], cc[7];
#pragma unroll
    for (int f = 0; f < 7; f++) {
        int pos = f * 16 + l15;
        rr[f] = pos / 28;
        cc[f] = pos - rr[f] * 28;
    }

    f32x4 acc[2][7];
#pragma unroll
    for (int g = 0; g < 2; g++)
#pragma unroll
        for (int f = 0; f < 7; f++) acc[g][f] = (f32x4){0.f, 0.f, 0.f, 0.f};

    bf16x8v ch0, cm0, cl0, ch1, cm1, cl1;
    bf16x8v nh0, nm0, nl0, nh1, nm1, nl1;
    {
        size_t b0 = ((size_t)0 * 16 + cf0) * 512 + lane * 8;
        ch0 = *(const bf16x8v*)(w1hip + b0);  cm0 = *(const bf16x8v*)(w1midp + b0);
        cl0 = *(const bf16x8v*)(w1lop + b0);
        ch1 = *(const bf16x8v*)(w1hip + b0 + 512); cm1 = *(const bf16x8v*)(w1midp + b0 + 512);
        cl1 = *(const bf16x8v*)(w1lop + b0 + 512);
        nh0 = ch0; nm0 = cm0; nl0 = cl0; nh1 = ch1; nm1 = cm1; nl1 = cl1;
    }

    for (int c = 0; c < 4; c++) {
        for (int tap = 0; tap < 9; tap++) {
            int rd = c * 9 + tap;
            if (rd < 35) {
                int rn = rd + 1, cn = rn / 9, tn = rn - cn * 9;
                size_t b0 = ((size_t)(tn * 4 + cn) * 16 + cf0) * 512 + lane * 8;
                nh0 = *(const bf16x8v*)(w1hip + b0);  nm0 = *(const bf16x8v*)(w1midp + b0);
                nl0 = *(const bf16x8v*)(w1lop + b0);
                nh1 = *(const bf16x8v*)(w1hip + b0 + 512); nm1 = *(const bf16x8v*)(w1midp + b0 + 512);
                nl1 = *(const bf16x8v*)(w1lop + b0 + 512);
            }
            const int kh = tap / 3, kw = tap - kh * 3;
#pragma unroll
            for (int f = 0; f < 7; f++) {
                unsigned int word = XW[c * 522 + (2 * rr[f] + kh) * 58 + 2 * cc[f] + kw];
                unsigned int byt  = (word >> (quad * 8)) & 0xffu;
                uint4 u;
                u.x = ((byt & 1u)   ? 0x3F80u : 0u) | ((byt & 2u)   ? 0x3F800000u : 0u);
                u.y = ((byt & 4u)   ? 0x3F80u : 0u) | ((byt & 8u)   ? 0x3F800000u : 0u);
                u.z = ((byt & 16u)  ? 0x3F80u : 0u) | ((byt & 32u)  ? 0x3F800000u : 0u);
                u.w = ((byt & 64u)  ? 0x3F80u : 0u) | ((byt & 128u) ? 0x3F800000u : 0u);
                union { uint4 q; bf16x8v v; } cv;
                cv.q = u;
                acc[0][f] = mfma16(ch0, cv.v, acc[0][f]);
                acc[0][f] = mfma16(cm0, cv.v, acc[0][f]);
                acc[0][f] = mfma16(cl0, cv.v, acc[0][f]);
                acc[1][f] = mfma16(ch1, cv.v, acc[1][f]);
                acc[1][f] = mfma16(cm1, cv.v, acc[1][f]);
                acc[1][f] = mfma16(cl1, cv.v, acc[1][f]);
            }
            ch0 = nh0; cm0 = nm0; cl0 = nl0; ch1 = nh1; cm1 = nm1; cl1 = nl1;
        }
    }

#pragma unroll
    for (int g = 0; g < 2; g++)
#pragma unroll
        for (int f = 0; f < 7; f++) {
            int pg = rt * 112 + f * 16 + l15;
#pragma unroll
            for (int reg = 0; reg < 4; reg++) {
                int co = cf0 * 16 + g * 16 + quad * 4 + reg;
                out[((size_t)n * CO + co) * P + pg] = acc[g][f][reg] + bias1[co];
            }
        }
}

// ---------------------------------------------------------------------------
// LIF1 + transpose: pre1 [16][8][256][784] fp32 ->
// spike_t [n][ch 8][pos 784][32ci] bf16, with the 4 ci-octets of each pos
// stored ROTATED by f8(pos) = ((((oh+1)*30 + ow + 1) >> 1) & 3 so conv2's
// DMA-landed LDS reads are conflict-free.
// ---------------------------------------------------------------------------
__global__ __launch_bounds__(256) void k_lif1t(
    const float* __restrict__ pre, unsigned short* __restrict__ st)
{
    __shared__ unsigned short T[16 * 68];
    const int b   = blockIdx.x;
    const int co0 = blockIdx.y * 64;
    const int p0  = blockIdx.z * 16;
    const int tid  = threadIdx.x;
    const int pcol = tid & 15;
    const int g    = tid >> 4;
    const int pos = p0 + g;
    const int oh  = pos / 28, ow = pos - oh * 28;
    const int f8  = ((((oh + 1) * 30 + ow + 1) >> 1) & 3);
    const int o      = (pcol & 7) >> 1;          // source octet
    const int no     = o ^ f8;                   // rotated octet slot
    const int within = (pcol & 1) * 4;
    const int chp    = (co0 >> 5) + (pcol >> 3);
    float v[4] = {0.f, 0.f, 0.f, 0.f};
    for (int t = 0; t < 8; t++) {
        const float* src = pre + (((size_t)(b * 8 + t)) * CO + co0) * P + p0;
        unsigned short s[4];
#pragma unroll
        for (int j = 0; j < 4; j++) {
            int co = g + 16 * j;
            float xv = src[(size_t)co * P + pcol];
            v[j] = v[j] + (xv - v[j]) * 0.5f;
            bool sp = v[j] > 1.0f;
            s[j] = sp ? 0x3F80 : 0;
            if (sp) v[j] = 0.f;
        }
        __syncthreads();
#pragma unroll
        for (int j = 0; j < 4; j++) T[pcol * 68 + g + 16 * j] = s[j];
        __syncthreads();
        unsigned short* dst = st + (((size_t)(b * 8 + t) * 8 + chp) * P + pos) * 32
                               + no * 8 + within;
        ushort4 ov;
        ov.x = T[g * 68 + pcol * 4 + 0];
        ov.y = T[g * 68 + pcol * 4 + 1];
        ov.z = T[g * 68 + pcol * 4 + 2];
        ov.w = T[g * 68 + pcol * 4 + 3];
        *(ushort4*)dst = ov;
    }
}

// ---------------------------------------------------------------------------
// conv2 3x3 s1 p1 + ds 1x1 s2 via bf16 MFMA (BN folded).
// R11: wave widened to 4 co-frags (64 co) — each LDS B-read feeds 56 MFMAs
// (was 28), halving LDS read demand per MFMA (the measured cap). Block
// covers all 256 co -> grid (896), spike DMA no longer duplicated.
// ds phase first (acc init), chunk-0 DMA hidden under it.
// ---------------------------------------------------------------------------
__global__ __launch_bounds__(256) void k_conv2_mfma(
    const unsigned short* __restrict__ spike_t,  // [128][8][784][32] rotated
    const unsigned int* __restrict__ xt_p,       // [128][3136][4]
    const unsigned short* __restrict__ w2hip,    // [9][8][16][64][8]
    const unsigned short* __restrict__ w2lop,
    const unsigned short* __restrict__ wdhip,    // [4][16][64][8]
    const unsigned short* __restrict__ wdlop,
    const float* __restrict__ bias2,
    float* __restrict__ out)                     // [128][256][784]
{
    __shared__ unsigned short SB[2 * 5760];      // 2 x 11520 B; line = 64B/slot
    __shared__ unsigned int   XW2[4 * 112];      // ds bit-words [ch][112 pos]

    const int n    = blockIdx.x / 7;
    const int rt   = blockIdx.x - n * 7;
    const int r0   = rt * 4;
    const int tid  = threadIdx.x;
    const int wave = tid >> 6;
    const int lane = tid & 63;
    const int l15  = lane & 15;
    const int quad = lane >> 4;
    const int cf0  = wave * 4;                   // 4 waves cover cf 0..15

    // zero both spike buffers (halo protocol) + stage ds bit-words
    {
        uint4 z = {0u, 0u, 0u, 0u};
        for (int i = tid; i < 1440; i += 256) ((uint4*)SB)[i] = z;
    }
    for (int i = tid; i < 112; i += 256) {
        int r = i / 28, c = i - r * 28;
        uint4 w4 = *(const uint4*)(xt_p + ((size_t)n * HWIN
                    + (2 * (r0 + r)) * WIN + 2 * c) * 4);
        XW2[0 * 112 + i] = w4.x;
        XW2[1 * 112 + i] = w4.y;
        XW2[2 * 112 + i] = w4.z;
        XW2[3 * 112 + i] = w4.w;
    }
    __syncthreads();                              // zeros + XW2 visible

    // DMA geometry: idx = wave*3+k in [0,12); row = idx>>1, half = idx&1
    int  g_irow[3], g_lds[3];
    bool g_ok[3];
    int  g_half[3];
#pragma unroll
    for (int k = 0; k < 3; k++) {
        int idx  = wave * 3 + k;
        int row  = idx >> 1, half = idx & 1;
        int irow = r0 - 1 + row;
        g_irow[k] = irow;
        g_half[k] = half;
        g_ok[k]   = ((unsigned)irow < 28u) && (half == 0 || lane < 48);
        g_lds[k]  = row * 1920 + 64 + half * 1024;   // wave-uniform
    }
    const char* sp_n = (const char*)spike_t + (size_t)n * 8 * P * 64;

    // issue chunk-0 DMA now; latency hides under the ds phase below
#pragma unroll
    for (int k = 0; k < 3; k++)
        if (g_ok[k])
            gld_lds16(sp_n + (size_t)g_irow[k] * 1792 + g_half[k] * 1024 + lane * 16,
                      (char*)SB + g_lds[k]);

    int rr[7], cc[7];
#pragma unroll
    for (int f = 0; f < 7; f++) {
        int pos = f * 16 + l15;
        rr[f] = pos / 28;
        cc[f] = pos - rr[f] * 28;
    }

    f32x4 acc[4][7];
#pragma unroll
    for (int g = 0; g < 4; g++)
#pragma unroll
        for (int f = 0; f < 7; f++) acc[g][f] = (f32x4){0.f, 0.f, 0.f, 0.f};

    // ---- ds phase (acc init): bit-unpack from XW2, wd regs die after ----
    for (int c = 0; c < 4; c++) {
        size_t b0 = ((size_t)c * 16 + cf0) * 512 + lane * 8;
        bf16x8v ah[4], al[4];
#pragma unroll
        for (int g = 0; g < 4; g++) {
            ah[g] = *(const bf16x8v*)(wdhip + b0 + g * 512);
            al[g] = *(const bf16x8v*)(wdlop + b0 + g * 512);
        }
#pragma unroll
        for (int f = 0; f < 7; f++) {
            unsigned int word = XW2[c * 112 + rr[f] * 28 + cc[f]];
            unsigned int byt  = (word >> (quad * 8)) & 0xffu;
            uint4 u;
            u.x = ((byt & 1u)   ? 0x3F80u : 0u) | ((byt & 2u)   ? 0x3F800000u : 0u);
            u.y = ((byt & 4u)   ? 0x3F80u : 0u) | ((byt & 8u)   ? 0x3F800000u : 0u);
            u.z = ((byt & 16u)  ? 0x3F80u : 0u) | ((byt & 32u)  ? 0x3F800000u : 0u);
            u.w = ((byt & 64u)  ? 0x3F80u : 0u) | ((byt & 128u) ? 0x3F800000u : 0u);
            union { uint4 q; bf16x8v v; } cv;
            cv.q = u;
#pragma unroll
            for (int g = 0; g < 4; g++) {
                acc[g][f] = mfma16(ah[g], cv.v, acc[g][f]);
                acc[g][f] = mfma16(al[g], cv.v, acc[g][f]);
            }
        }
    }
    __syncthreads();                              // drains chunk-0 DMA too

    // ---- main conv loop, double-buffered DMA, weight reg prefetch ----
    // cw[2g] = hi frag for cf0+g, cw[2g+1] = lo frag
    bf16x8v cw[8], nx[8];
    {
        size_t b0 = ((size_t)0 * 16 + cf0) * 512 + lane * 8;
#pragma unroll
        for (int g = 0; g < 4; g++) {
            cw[2 * g]     = *(const bf16x8v*)(w2hip + b0 + g * 512);
            cw[2 * g + 1] = *(const bf16x8v*)(w2lop + b0 + g * 512);
            nx[2 * g]     = cw[2 * g];
            nx[2 * g + 1] = cw[2 * g + 1];
        }
    }

    for (int c = 0; c < 8; c++) {
        if (c < 7) {                              // async stage chunk c+1
            const char* base = sp_n + (size_t)(c + 1) * 50176;
            char* dstb = (char*)SB + ((c + 1) & 1) * 11520;
#pragma unroll
            for (int k = 0; k < 3; k++)
                if (g_ok[k])
                    gld_lds16(base + (size_t)g_irow[k] * 1792 + g_half[k] * 1024 + lane * 16,
                              dstb + g_lds[k]);
        }
        const int bufsh = (c & 1) * 5760;
        for (int tap = 0; tap < 9; tap++) {
            int rd = c * 9 + tap;
            if (rd < 71) {
                int rn = rd + 1, cn = rn / 9, tn = rn - cn * 9;
                size_t b0 = ((size_t)(tn * 8 + cn) * 16 + cf0) * 512 + lane * 8;
#pragma unroll
                for (int g = 0; g < 4; g++) {
                    nx[2 * g]     = *(const bf16x8v*)(w2hip + b0 + g * 512);
                    nx[2 * g + 1] = *(const bf16x8v*)(w2lop + b0 + g * 512);
                }
            }
            const int kh = tap / 3, kw = tap - kh * 3;
#pragma unroll
            for (int f = 0; f < 7; f++) {
                int slot = (rr[f] + kh) * 30 + cc[f] + kw;
                int sw   = (slot >> 1) & 3;       // == producer rotation f8
                bf16x8v bfr = *(const bf16x8v*)(
                    &SB[bufsh + slot * 32 + ((quad ^ sw) * 8)]);
#pragma unroll
                for (int g = 0; g < 4; g++) {
                    acc[g][f] = mfma16(cw[2 * g], bfr, acc[g][f]);
                    acc[g][f] = mfma16(cw[2 * g + 1], bfr, acc[g][f]);
                }
            }
#pragma unroll
            for (int j = 0; j < 8; j++) cw[j] = nx[j];
        }
        __syncthreads();                          // release buf c, land c+1
    }

#pragma unroll
    for (int g = 0; g < 4; g++)
#pragma unroll
        for (int f = 0; f < 7; f++) {
            int pg = rt * 112 + f * 16 + l15;
#pragma unroll
            for (int reg = 0; reg < 4; reg++) {
                int co = (cf0 + g) * 16 + quad * 4 + reg;
                out[((size_t)n * CO + co) * P + pg] = acc[g][f][reg] + bias2[co];
            }
        }
}

// ---------------------------------------------------------------------------
// LIF2: in-place over [B=16, T=8, PERT], float4-vectorized
// ---------------------------------------------------------------------------
__global__ __launch_bounds__(256) void k_lif4(const float4* __restrict__ in,
                                              float4* __restrict__ out)
{
    const int q = PERT / 4;                       // 50176
    const int i = blockIdx.x * 256 + threadIdx.x;
    const int b = i / q;
    const int r = i - b * q;
    const float4* pi = in  + (size_t)(b * 8) * q + r;
    float4*       po = out + (size_t)(b * 8) * q + r;
    float v0 = 0.f, v1 = 0.f, v2 = 0.f, v3 = 0.f;
#pragma unroll
    for (int t = 0; t < 8; t++) {
        float4 xt = pi[(size_t)t * q];
        float4 s;
        v0 = v0 + (xt.x - v0) * 0.5f; s.x = (v0 > 1.0f) ? 1.f : 0.f; if (v0 > 1.0f) v0 = 0.f;
        v1 = v1 + (xt.y - v1) * 0.5f; s.y = (v1 > 1.0f) ? 1.f : 0.f; if (v1 > 1.0f) v1 = 0.f;
        v2 = v2 + (xt.z - v2) * 0.5f; s.z = (v2 > 1.0f) ? 1.f : 0.f; if (v2 > 1.0f) v2 = 0.f;
        v3 = v3 + (xt.w - v3) * 0.5f; s.w = (v3 > 1.0f) ? 1.f : 0.f; if (v3 > 1.0f) v3 = 0.f;
        po[(size_t)t * q] = s;
    }
}

extern "C" void kernel_launch(void* const* d_in, const int* in_sizes, int n_in,
                              void* d_out, int out_size, void* d_ws, size_t ws_size,
                              hipStream_t stream) {
    const float* x   = (const float*)d_in[0];
    const float* w1  = (const float*)d_in[1];
    const float* w2  = (const float*)d_in[2];
    const float* wd  = (const float*)d_in[3];
    const float* n1g = (const float*)d_in[4];
    const float* n1b = (const float*)d_in[5];
    const float* n1m = (const float*)d_in[6];
    const float* n1v = (const float*)d_in[7];
    const float* n2g = (const float*)d_in[8];
    const float* n2b = (const float*)d_in[9];
    const float* n2m = (const float*)d_in[10];
    const float* n2v = (const float*)d_in[11];
    const float* ndg = (const float*)d_in[12];
    const float* ndb = (const float*)d_in[13];
    const float* ndm = (const float*)d_in[14];
    const float* ndv = (const float*)d_in[15];

    float* out = (float*)d_out;   // pre1 -> (lif1t) -> pre2 -> final spikes

    // ws layout (1KB-aligned); total ~62.1 MB
    char* w = (char*)d_ws;
    unsigned short* spike_t = (unsigned short*)w;                    // 51,380,224
    unsigned short* w2hip   = (unsigned short*)(w + 51380224);       //  1,179,648
    unsigned short* w2lop   = (unsigned short*)(w + 52559872);       //  1,179,648
    unsigned short* w1hip   = (unsigned short*)(w + 53739520);       //    589,824
    unsigned short* w1midp  = (unsigned short*)(w + 54329344);       //    589,824
    unsigned short* w1lop   = (unsigned short*)(w + 54919168);       //    589,824
    unsigned short* wdhip   = (unsigned short*)(w + 55508992);       //     65,536
    unsigned short* wdlop   = (unsigned short*)(w + 55574528);       //     65,536
    float*          bias2   = (float*)(w + 55640064);
    float*          bias1   = (float*)(w + 55641088);
    float*          inv1    = (float*)(w + 55642112);
    float*          inv2    = (float*)(w + 55643136);
    float*          invd    = (float*)(w + 55644160);
    unsigned int*   xt_p    = (unsigned int*)(w + 55645184);         //  6,422,528

    k_prep_bias<<<1, 256, 0, stream>>>(n1g, n1b, n1m, n1v,
                                       n2g, n2b, n2m, n2v,
                                       ndg, ndb, ndm, ndv,
                                       inv1, bias1, inv2, invd, bias2);
    k_prep_w2p<<<288, 256, 0, stream>>>(w2, inv2, w2hip, w2lop);
    k_prep_w1p<<<144, 256, 0, stream>>>(w1, inv1, w1hip, w1midp, w1lop);
    k_prep_wdp<<<16, 256, 0, stream>>>(wd, invd, wdhip, wdlop);

    k_pack1<<<(128 * 4 * HWIN) / 256, 256, 0, stream>>>(x, xt_p);
    k_conv1_mfma<<<dim3(896, 2), 256, 0, stream>>>(
        xt_p, w1hip, w1midp, w1lop, bias1, out);
    k_lif1t<<<dim3(16, 4, 49), 256, 0, stream>>>(out, spike_t);
    k_conv2_mfma<<<dim3(896), 256, 0, stream>>>(
        spike_t, xt_p, w2hip, w2lop, wdhip, wdlop, bias2, out);
    k_lif4<<<(16 * (PERT / 4)) / 256, 256, 0, stream>>>(
        (const float4*)out, (float4*)out);
}